// Round 10
// baseline (533.329 us; speedup 1.0000x reference)
//
#include <hip/hip_runtime.h>
#include <stdint.h>
#include <stddef.h>

// VectorQuantization — N=32768, K=8192, D=256 fp32 -> int32 argmin.
// Round 14: clean hybrid-A test on the BEST structure. r4 (399 µs, session
// best) = BK=64, 2-barrier m97 loop, zero asm. Per-CU budget: MFMA 199 µs,
// LDS port 219 µs (reads 164 + DMA 55), wall = SUM (no overlap). r13's
// hybrid test was confounded (setprio m190, sched_barrier pinning m141,
// 3-buf). This round changes EXACTLY ONE thing vs r4: x fragments come from
// a PACKED global layout (r13-verified bit-exact) straight into registers,
// issued between STAGE and the barrier so L2 latency hides under the
// staging drain. LDS = codes only (32KB): reads halve 164->82, DMA halves
// 55->27 -> port 109 << MFMA 199; serialized floor ~330-350. B staging,
// swizzle, read pattern byte-identical to r4's measured-conflict-free ones.
// MFMA order (ks asc, dkc asc, kt asc, j-outer/i-inner, 3 terms) unchanged
// -> bit-identical results. No asm, no setprio.
// Fallback to the (passing) round-3 kernel if ws_size < 43MB.

#define N_PTS 32768
#define K_CB  8192
#define D_DIM 256
#define TM 128
#define TN 128
#define SPLITK 4
#define KCHUNK (K_CB / SPLITK)   // 2048
#define NTILES (KCHUNK / TN)     // 16

// fast-path ws layout (byte offsets; all 16B-aligned). xh/xl are PACKED:
// [row/64][kchunk 0..7][row%64][slot 0..3 (16B)] — same total bytes.
#define WS_XH   0
#define WS_XL   (WS_XH + N_PTS * D_DIM * 2)
#define WS_CH   (WS_XL + N_PTS * D_DIM * 2)
#define WS_CL   (WS_CH + K_CB * D_DIM * 2)
#define WS_C2   (WS_CL + K_CB * D_DIM * 2)
#define WS_PD   (WS_C2 + K_CB * 4)
#define WS_PI   (WS_PD + SPLITK * N_PTS * 4)
#define WS_END  (WS_PI + SPLITK * N_PTS * 4)   // 43,024,384 B

typedef _Float16 half4v __attribute__((ext_vector_type(4)));
typedef _Float16 half8v __attribute__((ext_vector_type(8)));
typedef float    f32x4  __attribute__((ext_vector_type(4)));

__device__ __forceinline__ void gld16(const void* g, void* l) {
    __builtin_amdgcn_global_load_lds(
        (const __attribute__((address_space(1))) void*)g,
        (__attribute__((address_space(3))) void*)l, 16, 0, 0);
}

// ---------------- preprocessing (fused: split x (packed), codes + norms) ---

#define XBLOCKS (N_PTS * D_DIM / 4 / 256)   // 8192
#define CBLOCKS (K_CB * D_DIM / 4 / 256)    // 2048

__global__ void __launch_bounds__(256)
prep_kernel(const float* __restrict__ x, const float* __restrict__ vecs,
            _Float16* __restrict__ xh, _Float16* __restrict__ xl,
            _Float16* __restrict__ ch, _Float16* __restrict__ cl,
            float* __restrict__ c2) {
    const int b = blockIdx.x;
    if (b < XBLOCKS) {
        const int i = b * 256 + threadIdx.x;           // one float4 per thread
        const float4 v = ((const float4*)x)[i];
        half4v h = {(_Float16)v.x, (_Float16)v.y, (_Float16)v.z, (_Float16)v.w};
        half4v l = {(_Float16)((v.x - (float)h[0]) * 2048.0f),
                    (_Float16)((v.y - (float)h[1]) * 2048.0f),
                    (_Float16)((v.z - (float)h[2]) * 2048.0f),
                    (_Float16)((v.w - (float)h[3]) * 2048.0f)};
        // packed fragment layout: row r, k k0 ->
        // ((r>>6)*8 + (k0>>5))*4096 + (r&63)*64 + ((k0>>3)&3)*16 + (k0&7)*2
        const int f   = i * 4;
        const int row = f >> 8, k0 = f & 255;
        const size_t pa = ((size_t)(row >> 6) * 8 + (k0 >> 5)) * 4096
                        + (row & 63) * 64 + ((k0 >> 3) & 3) * 16 + (k0 & 7) * 2;
        *(half4v*)((char*)xh + pa) = h;
        *(half4v*)((char*)xl + pa) = l;
    } else {
        const int i = (b - XBLOCKS) * 256 + threadIdx.x;
        const float4 v = ((const float4*)vecs)[i];
        half4v h = {(_Float16)v.x, (_Float16)v.y, (_Float16)v.z, (_Float16)v.w};
        half4v l = {(_Float16)((v.x - (float)h[0]) * 2048.0f),
                    (_Float16)((v.y - (float)h[1]) * 2048.0f),
                    (_Float16)((v.z - (float)h[2]) * 2048.0f),
                    (_Float16)((v.w - (float)h[3]) * 2048.0f)};
        *(half4v*)(ch + (size_t)i * 4) = h;
        *(half4v*)(cl + (size_t)i * 4) = l;
        // one wave == one code row -> norm (identical tree -> bit-identical c2)
        float s = v.x * v.x + v.y * v.y + v.z * v.z + v.w * v.w;
#pragma unroll
        for (int off = 32; off > 0; off >>= 1) s += __shfl_down(s, off, 64);
        if ((threadIdx.x & 63) == 0) c2[i >> 6] = s;
    }
}

// kept for the fallback path
__global__ void __launch_bounds__(256)
cnorms_kernel(const float* __restrict__ vecs, float* __restrict__ c2) {
    int gwave = (blockIdx.x * 256 + threadIdx.x) >> 6;   // one wave per code row
    int lane  = threadIdx.x & 63;
    const float* src = vecs + (size_t)gwave * D_DIM;
    float4 v = ((const float4*)src)[lane];
    float s = v.x * v.x + v.y * v.y + v.z * v.z + v.w * v.w;
#pragma unroll
    for (int off = 32; off > 0; off >>= 1) s += __shfl_down(s, off, 64);
    if (lane == 0) c2[gwave] = s;
}

// ---------------- fast main kernel (codes in LDS, x in registers) ---------

__global__ void __launch_bounds__(256, 2)
vq_main_fast(const _Float16* __restrict__ xh_p, const _Float16* __restrict__ xl_p,
             const _Float16* __restrict__ ch_g, const _Float16* __restrict__ cl_g,
             const float* __restrict__ c2, float* __restrict__ pd, int* __restrict__ pi) {
    // codes only: ch [0,16K), cl [16K,32K). 128B rows; 16B k-slot s of row r
    // holds k-group s^(r&7) — byte-identical to r4's measured-conflict-free
    // staging/read pattern (SQ_LDS_BANK_CONFLICT 8129).
    __shared__ __align__(16) char lds[32768];

    const int t    = threadIdx.x;
    const int lane = t & 63;
    const int wv   = t >> 6;
    const int wy   = wv >> 1, wx = wv & 1;   // wave quadrant of 128x128
    const int fr   = lane & 15;              // row/col within 16x16 tile
    const int g    = lane >> 4;              // k-group 0..3

    const int split = blockIdx.x & (SPLITK - 1);
    const int pbase = (blockIdx.x >> 2) * TM;
    const int kbase = split * KCHUNK;

    // codes staging (r4 pattern): lane i reads the 16B k-slot (i%8)^(i/8) of
    // row i/8 -> LDS image gets slot s of row r = k-group s^(r&7); global
    // 128B row chunks coalesce. 8 gld16 per wave per dkc.
    const int rowoff = (lane >> 3) * (D_DIM * 2) + (((lane & 7) ^ (lane >> 3)) << 4);
    char* ldsB_h = lds +         (wv * 32) * 128;   // wave-uniform DMA bases
    char* ldsB_l = lds + 16384 + (wv * 32) * 128;

    // x packed fragment base: grp = row/64 for this wave's 64-row strip
    const int grp = (blockIdx.x >> 2) * 2 + wy;
    const char* xhp = (const char*)xh_p + (size_t)grp * 32768 + fr * 64 + g * 16;
    const char* xlp = (const char*)xl_p + (size_t)grp * 32768 + fr * 64 + g * 16;

    // B fragment LDS byte offsets (constant across kt/dkc): row*128 + slot
    int boff[4][2];
#pragma unroll
    for (int j = 0; j < 4; ++j)
#pragma unroll
        for (int ks = 0; ks < 2; ++ks)
            boff[j][ks] = (wx * 64 + j * 16 + fr) * 128 + (((ks * 4 + g) ^ (fr & 7)) << 4);

    float best[16];
    int   bidx[16];
#pragma unroll
    for (int i = 0; i < 16; ++i) { best[i] = 3.4e38f; bidx[i] = 0; }

    for (int kt = 0; kt < NTILES; ++kt) {
        const int ktbase = kbase + kt * TN;
        const char* ch_w = (const char*)ch_g + (size_t)(ktbase + wv * 32) * (D_DIM * 2) + rowoff;
        const char* cl_w = (const char*)cl_g + (size_t)(ktbase + wv * 32) * (D_DIM * 2) + rowoff;

        f32x4 acc[4][4];
#pragma unroll
        for (int i = 0; i < 4; ++i)
#pragma unroll
            for (int j = 0; j < 4; ++j) {
                f32x4 z = {0.f, 0.f, 0.f, 0.f};
                acc[i][j] = z;
            }

#pragma unroll 1
        for (int dkc = 0; dkc < 4; ++dkc) {      // 64-halves K chunks
            const int gofs = dkc * 128;          // byte offset into each row
            __syncthreads();                      // readers of prev chunk done
#pragma unroll
            for (int q = 0; q < 4; ++q) {        // 8 rows per inst, 32 rows/wave
                gld16(ch_w + q * 4096 + gofs, ldsB_h + q * 1024);
                gld16(cl_w + q * 4096 + gofs, ldsB_l + q * 1024);
            }
            // A fragments from packed global -> registers; issued BEFORE the
            // barrier so L2 latency hides under the staging drain. These do
            // not touch LDS.
            half8v a1[2][4], a3[2][4];
#pragma unroll
            for (int ks = 0; ks < 2; ++ks) {
                const int xofs = (dkc * 2 + ks) * 4096;
#pragma unroll
                for (int i = 0; i < 4; ++i) {
                    a1[ks][i] = *(const half8v*)(xhp + xofs + i * 1024);
                    a3[ks][i] = *(const half8v*)(xlp + xofs + i * 1024);
                }
            }
            __syncthreads();                      // barrier drains vmcnt (m97)
#pragma unroll
            for (int ks = 0; ks < 2; ++ks) {
                half8v a2[4];
#pragma unroll
                for (int i = 0; i < 4; ++i)
                    a2[i] = a1[ks][i] * (_Float16)4.8828125e-4f; // xh*2^-11
#pragma unroll
                for (int j = 0; j < 4; ++j) {
                    const char* p = lds + boff[j][ks];
                    half8v b1 = *(const half8v*)p;              // ch
                    half8v b2 = *(const half8v*)(p + 16384);    // cl*2^11
                    half8v b3 = b1 * (_Float16)4.8828125e-4f;   // ch*2^-11
#pragma unroll
                    for (int i = 0; i < 4; ++i) {
                        acc[i][j] = __builtin_amdgcn_mfma_f32_16x16x32_f16(a1[ks][i], b1, acc[i][j], 0, 0, 0);
                        acc[i][j] = __builtin_amdgcn_mfma_f32_16x16x32_f16(a2[i],     b2, acc[i][j], 0, 0, 0);
                        acc[i][j] = __builtin_amdgcn_mfma_f32_16x16x32_f16(a3[ks][i], b3, acc[i][j], 0, 0, 0);
                    }
                }
            }
        }

        // merge tile into running argmin; ascending j + strict < == np first-min
#pragma unroll
        for (int j = 0; j < 4; ++j) {
            const int cg = ktbase + wx * 64 + j * 16 + fr;
            const float c2v = c2[cg];
#pragma unroll
            for (int i = 0; i < 4; ++i)
#pragma unroll
                for (int r = 0; r < 4; ++r) {
                    const float v = fmaf(-2.0f, acc[i][j][r], c2v);
                    const int s = i * 4 + r;
                    if (v < best[s]) { best[s] = v; bidx[s] = cg; }
                }
        }
    }

    // reduce across the 16 lanes holding each point row, then the 2 wave-cols
    __syncthreads();
    float* rd = (float*)lds;          // 128 x 2 floats
    int*   ri = (int*)lds + 256;      // 128 x 2 ints
#pragma unroll
    for (int i = 0; i < 4; ++i)
#pragma unroll
        for (int r = 0; r < 4; ++r) {
            float bv = best[i * 4 + r];
            int   bi = bidx[i * 4 + r];
#pragma unroll
            for (int off = 1; off < 16; off <<= 1) {
                const float ov = __shfl_xor(bv, off, 64);
                const int   oi = __shfl_xor(bi, off, 64);
                if (ov < bv || (ov == bv && oi < bi)) { bv = ov; bi = oi; }
            }
            if (fr == 0) {
                const int rowl = wy * 64 + i * 16 + g * 4 + r;
                rd[rowl * 2 + wx] = bv;
                ri[rowl * 2 + wx] = bi;
            }
        }
    __syncthreads();
    if (t < TM) {
        float b0 = rd[t * 2];
        int   i0 = ri[t * 2];
        const float b1 = rd[t * 2 + 1];
        const int   i1 = ri[t * 2 + 1];
        if (b1 < b0 || (b1 == b0 && i1 < i0)) { b0 = b1; i0 = i1; }
        pd[split * N_PTS + pbase + t] = b0;
        pi[split * N_PTS + pbase + t] = i0;
    }
}

// ---------------- fallback (round-3, passing) ----------------

#define BK 32
#define LS (BK + 4)

__device__ inline half8v load8(const _Float16* p) {
    half4v a = *(const half4v*)p;
    half4v b = *(const half4v*)(p + 4);
    return __builtin_shufflevector(a, b, 0, 1, 2, 3, 4, 5, 6, 7);
}

struct Trip { _Float16 h, s2, l2; };

__device__ inline Trip cvt3(float v) {
    Trip t;
    _Float16 hh = (_Float16)v;
    float hf = (float)hh;
    t.h  = hh;
    t.s2 = (_Float16)(hf * 4.8828125e-4f);
    t.l2 = (_Float16)((v - hf) * 2048.0f);
    return t;
}

__global__ void __launch_bounds__(256, 2)
vq_main_v3(const float* __restrict__ x, const float* __restrict__ vecs,
           const float* __restrict__ c2, float* __restrict__ pd, int* __restrict__ pi) {
    __shared__ _Float16 lds[6 * TM * LS];
    _Float16* xh  = lds;
    _Float16* xs2 = lds + 1 * TM * LS;
    _Float16* xl2 = lds + 2 * TM * LS;
    _Float16* ch  = lds + 3 * TM * LS;
    _Float16* cl2 = lds + 4 * TM * LS;
    _Float16* cs2 = lds + 5 * TM * LS;

    const int t     = threadIdx.x;
    const int split = blockIdx.x & (SPLITK - 1);
    const int pbase = (blockIdx.x >> 2) * TM;
    const int kbase = split * KCHUNK;

    const int lane = t & 63;
    const int wv   = t >> 6;
    const int wy   = wv >> 1, wx = wv & 1;
    const int fr   = lane & 15;
    const int g    = lane >> 4;
    const int kb   = g * 8;

    const int srow = t >> 3;
    const int sc4  = (t & 7) * 4;

    float best[16];
    int   bidx[16];
#pragma unroll
    for (int i = 0; i < 16; ++i) { best[i] = 3.4e38f; bidx[i] = 0; }

    for (int kt = 0; kt < NTILES; ++kt) {
        const int ktbase = kbase + kt * TN;
        f32x4 acc[4][4];
#pragma unroll
        for (int i = 0; i < 4; ++i)
#pragma unroll
            for (int j = 0; j < 4; ++j) {
                f32x4 z = {0.f, 0.f, 0.f, 0.f};
                acc[i][j] = z;
            }
        for (int dk = 0; dk < D_DIM; dk += BK) {
            __syncthreads();
#pragma unroll
            for (int p = 0; p < 4; ++p) {
                const int row = srow + p * 32;
                const float4 v = *(const float4*)&x[(size_t)(pbase + row) * D_DIM + dk + sc4];
                const Trip t0 = cvt3(v.x), t1 = cvt3(v.y), t2 = cvt3(v.z), t3 = cvt3(v.w);
                half4v h  = {t0.h,  t1.h,  t2.h,  t3.h};
                half4v s2 = {t0.s2, t1.s2, t2.s2, t3.s2};
                half4v l2 = {t0.l2, t1.l2, t2.l2, t3.l2};
                *(half4v*)&xh [row * LS + sc4] = h;
                *(half4v*)&xs2[row * LS + sc4] = s2;
                *(half4v*)&xl2[row * LS + sc4] = l2;
                const float4 w = *(const float4*)&vecs[(size_t)(ktbase + row) * D_DIM + dk + sc4];
                const Trip u0 = cvt3(w.x), u1 = cvt3(w.y), u2 = cvt3(w.z), u3 = cvt3(w.w);
                half4v hc = {u0.h,  u1.h,  u2.h,  u3.h};
                half4v sc = {u0.s2, u1.s2, u2.s2, u3.s2};
                half4v lc = {u0.l2, u1.l2, u2.l2, u3.l2};
                *(half4v*)&ch [row * LS + sc4] = hc;
                *(half4v*)&cs2[row * LS + sc4] = sc;
                *(half4v*)&cl2[row * LS + sc4] = lc;
            }
            __syncthreads();
            half8v a1[4], a2[4], a3[4], b1[4], b2[4], b3[4];
#pragma unroll
            for (int i = 0; i < 4; ++i) {
                const int aoff = (wy * 64 + i * 16 + fr) * LS + kb;
                a1[i] = load8(&xh [aoff]);
                a2[i] = load8(&xs2[aoff]);
                a3[i] = load8(&xl2[aoff]);
                const int boff2 = (wx * 64 + i * 16 + fr) * LS + kb;
                b1[i] = load8(&ch [boff2]);
                b2[i] = load8(&cl2[boff2]);
                b3[i] = load8(&cs2[boff2]);
            }
#pragma unroll
            for (int i = 0; i < 4; ++i)
#pragma unroll
                for (int j = 0; j < 4; ++j) {
                    acc[i][j] = __builtin_amdgcn_mfma_f32_16x16x32_f16(a1[i], b1[j], acc[i][j], 0, 0, 0);
                    acc[i][j] = __builtin_amdgcn_mfma_f32_16x16x32_f16(a2[i], b2[j], acc[i][j], 0, 0, 0);
                    acc[i][j] = __builtin_amdgcn_mfma_f32_16x16x32_f16(a3[i], b3[j], acc[i][j], 0, 0, 0);
                }
        }
#pragma unroll
        for (int j = 0; j < 4; ++j) {
            const int cg = ktbase + wx * 64 + j * 16 + fr;
            const float c2v = c2[cg];
#pragma unroll
            for (int i = 0; i < 4; ++i)
#pragma unroll
                for (int r = 0; r < 4; ++r) {
                    const float v = fmaf(-2.0f, acc[i][j][r], c2v);
                    const int s = i * 4 + r;
                    if (v < best[s]) { best[s] = v; bidx[s] = cg; }
                }
        }
    }
    __syncthreads();
    float* rd = (float*)lds;
    int*   ri = (int*)lds + 256;
#pragma unroll
    for (int i = 0; i < 4; ++i)
#pragma unroll
        for (int r = 0; r < 4; ++r) {
            float bv = best[i * 4 + r];
            int   bi = bidx[i * 4 + r];
#pragma unroll
            for (int off = 1; off < 16; off <<= 1) {
                const float ov = __shfl_xor(bv, off, 64);
                const int   oi = __shfl_xor(bi, off, 64);
                if (ov < bv || (ov == bv && oi < bi)) { bv = ov; bi = oi; }
            }
            if (fr == 0) {
                const int rowl = wy * 64 + i * 16 + g * 4 + r;
                rd[rowl * 2 + wx] = bv;
                ri[rowl * 2 + wx] = bi;
            }
        }
    __syncthreads();
    if (t < TM) {
        float b0 = rd[t * 2];
        int   i0 = ri[t * 2];
        const float b1 = rd[t * 2 + 1];
        const int   i1 = ri[t * 2 + 1];
        if (b1 < b0 || (b1 == b0 && i1 < i0)) { b0 = b1; i0 = i1; }
        pd[split * N_PTS + pbase + t] = b0;
        pi[split * N_PTS + pbase + t] = i0;
    }
}

// ---------------- combine ----------------

__global__ void __launch_bounds__(256)
vq_combine(const float* __restrict__ pd, const int* __restrict__ pi,
           int* __restrict__ out) {
    const int p = blockIdx.x * 256 + threadIdx.x;
    float bb = pd[p];
    int   bi = pi[p];
#pragma unroll
    for (int s = 1; s < SPLITK; ++s) {
        const float v  = pd[s * N_PTS + p];
        const int   vi = pi[s * N_PTS + p];
        if (v < bb || (v == bb && vi < bi)) { bb = v; bi = vi; }
    }
    out[p] = bi;
}

extern "C" void kernel_launch(void* const* d_in, const int* in_sizes, int n_in,
                              void* d_out, int out_size, void* d_ws, size_t ws_size,
                              hipStream_t stream) {
    const float* x    = (const float*)d_in[0];
    const float* vecs = (const float*)d_in[1];
    int* out = (int*)d_out;
    char* ws = (char*)d_ws;

    if (ws_size >= (size_t)WS_END) {
        _Float16* xh = (_Float16*)(ws + WS_XH);
        _Float16* xl = (_Float16*)(ws + WS_XL);
        _Float16* ch = (_Float16*)(ws + WS_CH);
        _Float16* cl = (_Float16*)(ws + WS_CL);
        float* c2 = (float*)(ws + WS_C2);
        float* pd = (float*)(ws + WS_PD);
        int*   pi = (int*)(ws + WS_PI);

        hipLaunchKernelGGL(prep_kernel, dim3(XBLOCKS + CBLOCKS), dim3(256), 0, stream,
                           x, vecs, xh, xl, ch, cl, c2);
        hipLaunchKernelGGL(vq_main_fast, dim3((N_PTS / TM) * SPLITK), dim3(256), 0, stream,
                           xh, xl, ch, cl, c2, pd, pi);
        hipLaunchKernelGGL(vq_combine, dim3(N_PTS / 256), dim3(256), 0, stream,
                           pd, pi, out);
    } else {
        float* c2 = (float*)ws;
        float* pd = (float*)ws + K_CB;
        int*   pi = (int*)((float*)ws + K_CB + SPLITK * N_PTS);
        hipLaunchKernelGGL(cnorms_kernel, dim3(K_CB / 4), dim3(256), 0, stream,
                           vecs, c2);
        hipLaunchKernelGGL(vq_main_v3, dim3((N_PTS / TM) * SPLITK), dim3(256), 0, stream,
                           x, vecs, c2, pd, pi);
        hipLaunchKernelGGL(vq_combine, dim3(N_PTS / 256), dim3(256), 0, stream,
                           pd, pi, out);
    }
}

// Round 11
// 497.393 us; speedup vs baseline: 1.0722x; 1.0722x over previous
//
#include <hip/hip_runtime.h>
#include <stdint.h>
#include <stddef.h>

// VectorQuantization — N=32768, K=8192, D=256 fp32 -> int32 argmin.
// Round 15: T3-minimum double-buffer at the RIGHT phase length. Established:
// wall(2-phase) = stage+drain+barrier serialized with MFMA (m233); r6 tested
// the dbuf recipe at BK=32 (compute 466cyc < latency ~600-900 -> failed);
// reg-prefetch of A gets SUNK by the compiler past barriers (r13/r14 VGPR
// 108/116 < live-set => loads moved into compute, latency exposed). Fix:
// BK=64 dbuf with ALL operands via global_load_lds (DMA can't be sunk),
// using CDNA4's 160KB LDS: one 512-thread block (8 waves = 2/SIMD, the m201
// template occupancy), 2 x 64KB buffers, ONE __syncthreads per chunk
// (64 barriers vs r4's 128). Every chunk's 64 gld16 get the full ~1860-cyc
// compute phase to land before the drain -> stage latency fully hidden.
// Wave grid 2Mx4N, wave tile 64x32 (acc 8 frags). Staging split: waves 0-3
// stage x rows, 4-7 stage codes (r4's proven conflict-free swizzle pattern,
// SQ_LDS_BANK_CONFLICT 8129). Per-output-element accumulation sequence
// (dkc asc, ks asc, terms 1-2-3, j-outer, i-inner) identical to r4 ->
// bit-identical results. No inline asm, no setprio.
// Fallback to the (passing) round-3 kernel if ws_size < 43MB.

#define N_PTS 32768
#define K_CB  8192
#define D_DIM 256
#define TM 128
#define TN 128
#define SPLITK 4
#define KCHUNK (K_CB / SPLITK)   // 2048
#define NTILES (KCHUNK / TN)     // 16
#define NCHUNKS (NTILES * 4)     // 64 BK=64 chunks per block

// fast-path ws layout (byte offsets; all 16B-aligned)
#define WS_XH   0
#define WS_XL   (WS_XH + N_PTS * D_DIM * 2)
#define WS_CH   (WS_XL + N_PTS * D_DIM * 2)
#define WS_CL   (WS_CH + K_CB * D_DIM * 2)
#define WS_C2   (WS_CL + K_CB * D_DIM * 2)
#define WS_PD   (WS_C2 + K_CB * 4)
#define WS_PI   (WS_PD + SPLITK * N_PTS * 4)
#define WS_END  (WS_PI + SPLITK * N_PTS * 4)   // 43,024,384 B

typedef _Float16 half4v __attribute__((ext_vector_type(4)));
typedef _Float16 half8v __attribute__((ext_vector_type(8)));
typedef float    f32x4  __attribute__((ext_vector_type(4)));

__device__ __forceinline__ void gld16(const void* g, void* l) {
    __builtin_amdgcn_global_load_lds(
        (const __attribute__((address_space(1))) void*)g,
        (__attribute__((address_space(3))) void*)l, 16, 0, 0);
}

// ---------------- preprocessing (fused: split x, split codes + norms) ------

#define XBLOCKS (N_PTS * D_DIM / 4 / 256)   // 8192
#define CBLOCKS (K_CB * D_DIM / 4 / 256)    // 2048

__global__ void __launch_bounds__(256)
prep_kernel(const float* __restrict__ x, const float* __restrict__ vecs,
            _Float16* __restrict__ xh, _Float16* __restrict__ xl,
            _Float16* __restrict__ ch, _Float16* __restrict__ cl,
            float* __restrict__ c2) {
    const int b = blockIdx.x;
    if (b < XBLOCKS) {
        const int i = b * 256 + threadIdx.x;           // one float4 per thread
        const float4 v = ((const float4*)x)[i];
        half4v h = {(_Float16)v.x, (_Float16)v.y, (_Float16)v.z, (_Float16)v.w};
        half4v l = {(_Float16)((v.x - (float)h[0]) * 2048.0f),
                    (_Float16)((v.y - (float)h[1]) * 2048.0f),
                    (_Float16)((v.z - (float)h[2]) * 2048.0f),
                    (_Float16)((v.w - (float)h[3]) * 2048.0f)};
        *(half4v*)(xh + (size_t)i * 4) = h;
        *(half4v*)(xl + (size_t)i * 4) = l;
    } else {
        const int i = (b - XBLOCKS) * 256 + threadIdx.x;
        const float4 v = ((const float4*)vecs)[i];
        half4v h = {(_Float16)v.x, (_Float16)v.y, (_Float16)v.z, (_Float16)v.w};
        half4v l = {(_Float16)((v.x - (float)h[0]) * 2048.0f),
                    (_Float16)((v.y - (float)h[1]) * 2048.0f),
                    (_Float16)((v.z - (float)h[2]) * 2048.0f),
                    (_Float16)((v.w - (float)h[3]) * 2048.0f)};
        *(half4v*)(ch + (size_t)i * 4) = h;
        *(half4v*)(cl + (size_t)i * 4) = l;
        // one wave == one code row (64 lanes x float4 = 256 floats) -> norm.
        float s = v.x * v.x + v.y * v.y + v.z * v.z + v.w * v.w;
#pragma unroll
        for (int off = 32; off > 0; off >>= 1) s += __shfl_down(s, off, 64);
        if ((threadIdx.x & 63) == 0) c2[i >> 6] = s;
    }
}

// kept for the fallback path
__global__ void __launch_bounds__(256)
cnorms_kernel(const float* __restrict__ vecs, float* __restrict__ c2) {
    int gwave = (blockIdx.x * 256 + threadIdx.x) >> 6;   // one wave per code row
    int lane  = threadIdx.x & 63;
    const float* src = vecs + (size_t)gwave * D_DIM;
    float4 v = ((const float4*)src)[lane];
    float s = v.x * v.x + v.y * v.y + v.z * v.z + v.w * v.w;
#pragma unroll
    for (int off = 32; off > 0; off >>= 1) s += __shfl_down(s, off, 64);
    if (lane == 0) c2[gwave] = s;
}

// ---------------- fast main kernel (BK=64 double-buffer, 8 waves) ----------

__global__ void __launch_bounds__(512, 2)
vq_main_fast(const _Float16* __restrict__ xh_g, const _Float16* __restrict__ xl_g,
             const _Float16* __restrict__ ch_g, const _Float16* __restrict__ cl_g,
             const float* __restrict__ c2, float* __restrict__ pd, int* __restrict__ pi) {
    // two 64KB buffers; per buffer: xh [0,16K) xl [16K,32K) ch [32K,48K)
    // cl [48K,64K). 128B rows; 16B k-slot s of row r holds k-group s^(r&7)
    // (r4's measured conflict-free pattern).
    __shared__ __align__(16) char lds[131072];

    const int t    = threadIdx.x;
    const int lane = t & 63;
    const int wv   = t >> 6;                 // 8 waves
    const int wy   = wv >> 2, wx = wv & 3;   // 2M x 4N; wave tile 64x32
    const int fr   = lane & 15;              // row/col within 16x16 tile
    const int g    = lane >> 4;              // k-group 0..3

    const int split = blockIdx.x & (SPLITK - 1);
    const int pbase = (blockIdx.x >> 2) * TM;
    const int kbase = split * KCHUNK;

    // staging roles: waves 0-3 stage x rows sw*32..+31; waves 4-7 stage codes.
    // lane i reads the 16B k-slot (i%8)^(i/8) of row i/8 (r4 pattern).
    const int sw = wv & 3;                   // row group within the tile
    const int sa = wv >> 2;                  // 0: x, 1: codes
    const int rowoff = (lane >> 3) * 512 + (((lane & 7) ^ (lane >> 3)) << 4);
    const char* srcH = sa ? (const char*)ch_g + (size_t)(kbase + sw * 32) * 512 + rowoff
                          : (const char*)xh_g + (size_t)(pbase + sw * 32) * 512 + rowoff;
    const char* srcL = sa ? (const char*)cl_g + (size_t)(kbase + sw * 32) * 512 + rowoff
                          : (const char*)xl_g + (size_t)(pbase + sw * 32) * 512 + rowoff;
    const int dstH = sa ? 32768 : 0;
    const int dstL = sa ? 49152 : 16384;
    const int dstW = sw * 4096;              // 32 rows x 128B

    // fragment LDS byte offsets (buffer-relative): row*128 + swizzled slot
    int aoff[4][2], boff[2][2];
#pragma unroll
    for (int i = 0; i < 4; ++i)
#pragma unroll
        for (int ks = 0; ks < 2; ++ks)
            aoff[i][ks] = (wy * 64 + i * 16 + fr) * 128 + (((ks * 4 + g) ^ (fr & 7)) << 4);
#pragma unroll
    for (int j = 0; j < 2; ++j)
#pragma unroll
        for (int ks = 0; ks < 2; ++ks)
            boff[j][ks] = 32768 + (wx * 32 + j * 16 + fr) * 128 + (((ks * 4 + g) ^ (fr & 7)) << 4);

    f32x4 acc[4][2];

    // chunk c = kt*4 + dkc; buffer = c&1. 8 gld16 per wave per chunk (64KB total).
    auto STAGE = [&](int bsel, int c) {
        const size_t koff = sa ? (size_t)(c >> 2) * (TN * 512) : 0;  // kt tile (codes only)
        const int gofs = (c & 3) * 128;                              // byte offset in row
        char* dst = lds + (bsel << 16) + dstW;
#pragma unroll
        for (int q = 0; q < 4; ++q) {
            gld16(srcH + koff + gofs + q * 4096, dst + dstH + q * 1024);
            gld16(srcL + koff + gofs + q * 4096, dst + dstL + q * 1024);
        }
    };

    auto COMPUTE = [&](int bo) {
#pragma unroll
        for (int ks = 0; ks < 2; ++ks) {
            half8v a1[4], a2[4], a3[4];
#pragma unroll
            for (int i = 0; i < 4; ++i) {
                const char* p = lds + bo + aoff[i][ks];
                a1[i] = *(const half8v*)p;                  // xh
                a3[i] = *(const half8v*)(p + 16384);        // xl*2^11
                a2[i] = a1[i] * (_Float16)4.8828125e-4f;    // xh*2^-11
            }
#pragma unroll
            for (int j = 0; j < 2; ++j) {
                const char* p = lds + bo + boff[j][ks];
                half8v b1 = *(const half8v*)p;              // ch
                half8v b2 = *(const half8v*)(p + 16384);    // cl*2^11
                half8v b3 = b1 * (_Float16)4.8828125e-4f;   // ch*2^-11
#pragma unroll
                for (int i = 0; i < 4; ++i) {
                    acc[i][j] = __builtin_amdgcn_mfma_f32_16x16x32_f16(a1[i], b1, acc[i][j], 0, 0, 0);
                    acc[i][j] = __builtin_amdgcn_mfma_f32_16x16x32_f16(a2[i], b2, acc[i][j], 0, 0, 0);
                    acc[i][j] = __builtin_amdgcn_mfma_f32_16x16x32_f16(a3[i], b3, acc[i][j], 0, 0, 0);
                }
            }
        }
    };

    float best[16];
    int   bidx[16];
#pragma unroll
    for (int i = 0; i < 16; ++i) { best[i] = 3.4e38f; bidx[i] = 0; }

    STAGE(0, 0);                  // prologue: chunk 0 in flight
    __syncthreads();              // drains vmcnt -> buffer 0 ready

#pragma unroll 1
    for (int kt = 0; kt < NTILES; ++kt) {
#pragma unroll
        for (int i = 0; i < 4; ++i)
#pragma unroll
            for (int j = 0; j < 2; ++j) {
                f32x4 z = {0.f, 0.f, 0.f, 0.f};
                acc[i][j] = z;
            }

#pragma unroll 1
        for (int dkc = 0; dkc < 4; ++dkc) {
            const int c = kt * 4 + dkc;
            // prefetch next chunk into the other buffer; its readers finished
            // at the barrier ending chunk c-1, and its loads get the whole
            // compute phase (~1860 cyc) to land before the next drain.
            if (c + 1 < NCHUNKS) STAGE((c + 1) & 1, c + 1);
            COMPUTE((c & 1) << 16);
            __syncthreads();      // vmcnt(0)+barrier: chunk c+1 ready, readers done
        }

        // merge tile into running argmin; ascending j + strict < == np first-min
        const int ktbase = kbase + kt * TN;
#pragma unroll
        for (int j = 0; j < 2; ++j) {
            const int cg = ktbase + wx * 32 + j * 16 + fr;
            const float c2v = c2[cg];
#pragma unroll
            for (int i = 0; i < 4; ++i)
#pragma unroll
                for (int r = 0; r < 4; ++r) {
                    const float v = fmaf(-2.0f, acc[i][j][r], c2v);
                    const int s = i * 4 + r;
                    if (v < best[s]) { best[s] = v; bidx[s] = cg; }
                }
        }
    }

    // reduce across the 16 lanes holding each point row, then the 4 wave-cols
    float* rd = (float*)lds;          // 128 x 4 floats
    int*   ri = (int*)lds + 512;      // 128 x 4 ints
#pragma unroll
    for (int i = 0; i < 4; ++i)
#pragma unroll
        for (int r = 0; r < 4; ++r) {
            float bv = best[i * 4 + r];
            int   bi = bidx[i * 4 + r];
#pragma unroll
            for (int off = 1; off < 16; off <<= 1) {
                const float ov = __shfl_xor(bv, off, 64);
                const int   oi = __shfl_xor(bi, off, 64);
                if (ov < bv || (ov == bv && oi < bi)) { bv = ov; bi = oi; }
            }
            if (fr == 0) {
                const int rowl = wy * 64 + i * 16 + g * 4 + r;
                rd[rowl * 4 + wx] = bv;
                ri[rowl * 4 + wx] = bi;
            }
        }
    __syncthreads();
    if (t < TM) {
        float b0 = rd[t * 4];
        int   i0 = ri[t * 4];
#pragma unroll
        for (int s = 1; s < 4; ++s) {
            const float b1 = rd[t * 4 + s];
            const int   i1 = ri[t * 4 + s];
            if (b1 < b0 || (b1 == b0 && i1 < i0)) { b0 = b1; i0 = i1; }
        }
        pd[split * N_PTS + pbase + t] = b0;
        pi[split * N_PTS + pbase + t] = i0;
    }
}

// ---------------- fallback (round-3, passing) ----------------

#define BK 32
#define LS (BK + 4)

__device__ inline half8v load8(const _Float16* p) {
    half4v a = *(const half4v*)p;
    half4v b = *(const half4v*)(p + 4);
    return __builtin_shufflevector(a, b, 0, 1, 2, 3, 4, 5, 6, 7);
}

struct Trip { _Float16 h, s2, l2; };

__device__ inline Trip cvt3(float v) {
    Trip t;
    _Float16 hh = (_Float16)v;
    float hf = (float)hh;
    t.h  = hh;
    t.s2 = (_Float16)(hf * 4.8828125e-4f);
    t.l2 = (_Float16)((v - hf) * 2048.0f);
    return t;
}

__global__ void __launch_bounds__(256, 2)
vq_main_v3(const float* __restrict__ x, const float* __restrict__ vecs,
           const float* __restrict__ c2, float* __restrict__ pd, int* __restrict__ pi) {
    __shared__ _Float16 lds[6 * TM * LS];
    _Float16* xh  = lds;
    _Float16* xs2 = lds + 1 * TM * LS;
    _Float16* xl2 = lds + 2 * TM * LS;
    _Float16* ch  = lds + 3 * TM * LS;
    _Float16* cl2 = lds + 4 * TM * LS;
    _Float16* cs2 = lds + 5 * TM * LS;

    const int t     = threadIdx.x;
    const int split = blockIdx.x & (SPLITK - 1);
    const int pbase = (blockIdx.x >> 2) * TM;
    const int kbase = split * KCHUNK;

    const int lane = t & 63;
    const int wv   = t >> 6;
    const int wy   = wv >> 1, wx = wv & 1;
    const int fr   = lane & 15;
    const int g    = lane >> 4;
    const int kb   = g * 8;

    const int srow = t >> 3;
    const int sc4  = (t & 7) * 4;

    float best[16];
    int   bidx[16];
#pragma unroll
    for (int i = 0; i < 16; ++i) { best[i] = 3.4e38f; bidx[i] = 0; }

    for (int kt = 0; kt < NTILES; ++kt) {
        const int ktbase = kbase + kt * TN;
        f32x4 acc[4][4];
#pragma unroll
        for (int i = 0; i < 4; ++i)
#pragma unroll
            for (int j = 0; j < 4; ++j) {
                f32x4 z = {0.f, 0.f, 0.f, 0.f};
                acc[i][j] = z;
            }
        for (int dk = 0; dk < D_DIM; dk += BK) {
            __syncthreads();
#pragma unroll
            for (int p = 0; p < 4; ++p) {
                const int row = srow + p * 32;
                const float4 v = *(const float4*)&x[(size_t)(pbase + row) * D_DIM + dk + sc4];
                const Trip t0 = cvt3(v.x), t1 = cvt3(v.y), t2 = cvt3(v.z), t3 = cvt3(v.w);
                half4v h  = {t0.h,  t1.h,  t2.h,  t3.h};
                half4v s2 = {t0.s2, t1.s2, t2.s2, t3.s2};
                half4v l2 = {t0.l2, t1.l2, t2.l2, t3.l2};
                *(half4v*)&xh [row * LS + sc4] = h;
                *(half4v*)&xs2[row * LS + sc4] = s2;
                *(half4v*)&xl2[row * LS + sc4] = l2;
                const float4 w = *(const float4*)&vecs[(size_t)(ktbase + row) * D_DIM + dk + sc4];
                const Trip u0 = cvt3(w.x), u1 = cvt3(w.y), u2 = cvt3(w.z), u3 = cvt3(w.w);
                half4v hc = {u0.h,  u1.h,  u2.h,  u3.h};
                half4v sc = {u0.s2, u1.s2, u2.s2, u3.s2};
                half4v lc = {u0.l2, u1.l2, u2.l2, u3.l2};
                *(half4v*)&ch [row * LS + sc4] = hc;
                *(half4v*)&cs2[row * LS + sc4] = sc;
                *(half4v*)&cl2[row * LS + sc4] = lc;
            }
            __syncthreads();
            half8v a1[4], a2[4], a3[4], b1[4], b2[4], b3[4];
#pragma unroll
            for (int i = 0; i < 4; ++i) {
                const int aoff = (wy * 64 + i * 16 + fr) * LS + kb;
                a1[i] = load8(&xh [aoff]);
                a2[i] = load8(&xs2[aoff]);
                a3[i] = load8(&xl2[aoff]);
                const int boff2 = (wx * 64 + i * 16 + fr) * LS + kb;
                b1[i] = load8(&ch [boff2]);
                b2[i] = load8(&cl2[boff2]);
                b3[i] = load8(&cs2[boff2]);
            }
#pragma unroll
            for (int i = 0; i < 4; ++i)
#pragma unroll
                for (int j = 0; j < 4; ++j) {
                    acc[i][j] = __builtin_amdgcn_mfma_f32_16x16x32_f16(a1[i], b1[j], acc[i][j], 0, 0, 0);
                    acc[i][j] = __builtin_amdgcn_mfma_f32_16x16x32_f16(a2[i], b2[j], acc[i][j], 0, 0, 0);
                    acc[i][j] = __builtin_amdgcn_mfma_f32_16x16x32_f16(a3[i], b3[j], acc[i][j], 0, 0, 0);
                }
        }
#pragma unroll
        for (int j = 0; j < 4; ++j) {
            const int cg = ktbase + wx * 64 + j * 16 + fr;
            const float c2v = c2[cg];
#pragma unroll
            for (int i = 0; i < 4; ++i)
#pragma unroll
                for (int r = 0; r < 4; ++r) {
                    const float v = fmaf(-2.0f, acc[i][j][r], c2v);
                    const int s = i * 4 + r;
                    if (v < best[s]) { best[s] = v; bidx[s] = cg; }
                }
        }
    }
    __syncthreads();
    float* rd = (float*)lds;
    int*   ri = (int*)lds + 256;
#pragma unroll
    for (int i = 0; i < 4; ++i)
#pragma unroll
        for (int r = 0; r < 4; ++r) {
            float bv = best[i * 4 + r];
            int   bi = bidx[i * 4 + r];
#pragma unroll
            for (int off = 1; off < 16; off <<= 1) {
                const float ov = __shfl_xor(bv, off, 64);
                const int   oi = __shfl_xor(bi, off, 64);
                if (ov < bv || (ov == bv && oi < bi)) { bv = ov; bi = oi; }
            }
            if (fr == 0) {
                const int rowl = wy * 64 + i * 16 + g * 4 + r;
                rd[rowl * 2 + wx] = bv;
                ri[rowl * 2 + wx] = bi;
            }
        }
    __syncthreads();
    if (t < TM) {
        float b0 = rd[t * 2];
        int   i0 = ri[t * 2];
        const float b1 = rd[t * 2 + 1];
        const int   i1 = ri[t * 2 + 1];
        if (b1 < b0 || (b1 == b0 && i1 < i0)) { b0 = b1; i0 = i1; }
        pd[split * N_PTS + pbase + t] = b0;
        pi[split * N_PTS + pbase + t] = i0;
    }
}

// ---------------- combine ----------------

__global__ void __launch_bounds__(256)
vq_combine(const float* __restrict__ pd, const int* __restrict__ pi,
           int* __restrict__ out) {
    const int p = blockIdx.x * 256 + threadIdx.x;
    float bb = pd[p];
    int   bi = pi[p];
#pragma unroll
    for (int s = 1; s < SPLITK; ++s) {
        const float v  = pd[s * N_PTS + p];
        const int   vi = pi[s * N_PTS + p];
        if (v < bb || (v == bb && vi < bi)) { bb = v; bi = vi; }
    }
    out[p] = bi;
}

extern "C" void kernel_launch(void* const* d_in, const int* in_sizes, int n_in,
                              void* d_out, int out_size, void* d_ws, size_t ws_size,
                              hipStream_t stream) {
    const float* x    = (const float*)d_in[0];
    const float* vecs = (const float*)d_in[1];
    int* out = (int*)d_out;
    char* ws = (char*)d_ws;

    if (ws_size >= (size_t)WS_END) {
        _Float16* xh = (_Float16*)(ws + WS_XH);
        _Float16* xl = (_Float16*)(ws + WS_XL);
        _Float16* ch = (_Float16*)(ws + WS_CH);
        _Float16* cl = (_Float16*)(ws + WS_CL);
        float* c2 = (float*)(ws + WS_C2);
        float* pd = (float*)(ws + WS_PD);
        int*   pi = (int*)(ws + WS_PI);

        hipLaunchKernelGGL(prep_kernel, dim3(XBLOCKS + CBLOCKS), dim3(256), 0, stream,
                           x, vecs, xh, xl, ch, cl, c2);
        hipLaunchKernelGGL(vq_main_fast, dim3((N_PTS / TM) * SPLITK), dim3(512), 0, stream,
                           xh, xl, ch, cl, c2, pd, pi);
        hipLaunchKernelGGL(vq_combine, dim3(N_PTS / 256), dim3(256), 0, stream,
                           pd, pi, out);
    } else {
        float* c2 = (float*)ws;
        float* pd = (float*)ws + K_CB;
        int*   pi = (int*)((float*)ws + K_CB + SPLITK * N_PTS);
        hipLaunchKernelGGL(cnorms_kernel, dim3(K_CB / 4), dim3(256), 0, stream,
                           vecs, c2);
        hipLaunchKernelGGL(vq_main_v3, dim3((N_PTS / TM) * SPLITK), dim3(256), 0, stream,
                           x, vecs, c2, pd, pi);
        hipLaunchKernelGGL(vq_combine, dim3(N_PTS / 256), dim3(256), 0, stream,
                           pd, pi, out);
    }
}

// Round 12
// 463.330 us; speedup vs baseline: 1.1511x; 1.0735x over previous
//
#include <hip/hip_runtime.h>
#include <stdint.h>
#include <stddef.h>

// VectorQuantization — N=32768, K=8192, D=256 fp32 -> int32 argmin.
// Round 16: RESTORE THE CHAMPION. Twelve structural variants (r5-r15) tested
// every bottleneck theory — dbuf/counted-vmcnt pipelines (r6/r8/r15), MFMA
// shape (r7), occupancy (r9/r11), LDS-port reduction via hybrid or
// all-register operand paths (r12/r13/r14) — and ALL landed at 413-1007 µs
// vs r4's 399 µs, with MFMA busy pinned at the 194-199 µs arithmetic floor
// throughout. r4's configuration (BK=64, plain 2-barrier m97 loop, 4 waves,
// 2 independent blocks/CU for cross-block overlap, both-sides XOR swizzle
// measured conflict-free at 8129) is the empirical optimum of this structure
// family; its ~49% MfmaUtil matches the documented 2-phase structural
// ceiling (m97/m233). This round: the r4 main kernel BYTE-IDENTICAL to the
// round-0 champion, plus the one clean orthogonal win from this session —
// fused preprocessing (split x + split codes + cnorms in ONE launch,
// verified bit-exact across r5-r15; saves ~25-30 µs of launch/traffic).
// Fallback to the (passing) round-3 kernel if ws_size < 43MB.

#define N_PTS 32768
#define K_CB  8192
#define D_DIM 256
#define TM 128
#define TN 128
#define SPLITK 4
#define KCHUNK (K_CB / SPLITK)   // 2048
#define NTILES (KCHUNK / TN)     // 16

// fast-path ws layout (byte offsets; all 16B-aligned)
#define WS_XH   0
#define WS_XL   (WS_XH + N_PTS * D_DIM * 2)
#define WS_CH   (WS_XL + N_PTS * D_DIM * 2)
#define WS_CL   (WS_CH + K_CB * D_DIM * 2)
#define WS_C2   (WS_CL + K_CB * D_DIM * 2)
#define WS_PD   (WS_C2 + K_CB * 4)
#define WS_PI   (WS_PD + SPLITK * N_PTS * 4)
#define WS_END  (WS_PI + SPLITK * N_PTS * 4)   // 43,024,384 B

typedef _Float16 half4v __attribute__((ext_vector_type(4)));
typedef _Float16 half8v __attribute__((ext_vector_type(8)));
typedef float    f32x4  __attribute__((ext_vector_type(4)));

__device__ __forceinline__ void gld16(const void* g, void* l) {
    __builtin_amdgcn_global_load_lds(
        (const __attribute__((address_space(1))) void*)g,
        (__attribute__((address_space(3))) void*)l, 16, 0, 0);
}

// ---------------- preprocessing (fused: split x, split codes + norms) ------

#define XBLOCKS (N_PTS * D_DIM / 4 / 256)   // 8192
#define CBLOCKS (K_CB * D_DIM / 4 / 256)    // 2048

__global__ void __launch_bounds__(256)
prep_kernel(const float* __restrict__ x, const float* __restrict__ vecs,
            _Float16* __restrict__ xh, _Float16* __restrict__ xl,
            _Float16* __restrict__ ch, _Float16* __restrict__ cl,
            float* __restrict__ c2) {
    const int b = blockIdx.x;
    if (b < XBLOCKS) {
        const int i = b * 256 + threadIdx.x;           // one float4 per thread
        const float4 v = ((const float4*)x)[i];
        half4v h = {(_Float16)v.x, (_Float16)v.y, (_Float16)v.z, (_Float16)v.w};
        half4v l = {(_Float16)((v.x - (float)h[0]) * 2048.0f),
                    (_Float16)((v.y - (float)h[1]) * 2048.0f),
                    (_Float16)((v.z - (float)h[2]) * 2048.0f),
                    (_Float16)((v.w - (float)h[3]) * 2048.0f)};
        *(half4v*)(xh + (size_t)i * 4) = h;
        *(half4v*)(xl + (size_t)i * 4) = l;
    } else {
        const int i = (b - XBLOCKS) * 256 + threadIdx.x;
        const float4 v = ((const float4*)vecs)[i];
        half4v h = {(_Float16)v.x, (_Float16)v.y, (_Float16)v.z, (_Float16)v.w};
        half4v l = {(_Float16)((v.x - (float)h[0]) * 2048.0f),
                    (_Float16)((v.y - (float)h[1]) * 2048.0f),
                    (_Float16)((v.z - (float)h[2]) * 2048.0f),
                    (_Float16)((v.w - (float)h[3]) * 2048.0f)};
        *(half4v*)(ch + (size_t)i * 4) = h;
        *(half4v*)(cl + (size_t)i * 4) = l;
        // one wave == one code row (64 lanes x float4 = 256 floats) -> norm.
        // identical reduction tree to the original cnorms -> bit-identical c2.
        float s = v.x * v.x + v.y * v.y + v.z * v.z + v.w * v.w;
#pragma unroll
        for (int off = 32; off > 0; off >>= 1) s += __shfl_down(s, off, 64);
        if ((threadIdx.x & 63) == 0) c2[i >> 6] = s;
    }
}

// kept for the fallback path
__global__ void __launch_bounds__(256)
cnorms_kernel(const float* __restrict__ vecs, float* __restrict__ c2) {
    int gwave = (blockIdx.x * 256 + threadIdx.x) >> 6;   // one wave per code row
    int lane  = threadIdx.x & 63;
    const float* src = vecs + (size_t)gwave * D_DIM;
    float4 v = ((const float4*)src)[lane];
    float s = v.x * v.x + v.y * v.y + v.z * v.z + v.w * v.w;
#pragma unroll
    for (int off = 32; off > 0; off >>= 1) s += __shfl_down(s, off, 64);
    if (lane == 0) c2[gwave] = s;
}

// ---------------- fast main kernel (r4 champion, byte-identical) ----------

__global__ void __launch_bounds__(256, 2)
vq_main_fast(const _Float16* __restrict__ xh_g, const _Float16* __restrict__ xl_g,
             const _Float16* __restrict__ ch_g, const _Float16* __restrict__ cl_g,
             const float* __restrict__ c2, float* __restrict__ pd, int* __restrict__ pi) {
    // regions: xh [0,16K), xl [16K,32K), ch [32K,48K), cl [48K,64K)
    __shared__ __align__(16) char lds[65536];

    const int t    = threadIdx.x;
    const int lane = t & 63;
    const int wv   = t >> 6;
    const int wy   = wv >> 1, wx = wv & 1;   // wave quadrant of 128x128
    const int fr   = lane & 15;              // row/col within 16x16 tile
    const int g    = lane >> 4;              // k-group 0..3

    const int split = blockIdx.x & (SPLITK - 1);
    const int pbase = (blockIdx.x >> 2) * TM;
    const int kbase = split * KCHUNK;

    // staging: per-lane source offset inside an 8-row block. lane i reads the
    // 16B k-slot k16 = (i%8)^(i/8) of row i/8 -> 8-lane groups cover one
    // contiguous 128B row chunk (perfect coalescing), and the LDS image gets
    // slot s of row r = k-group s^(r&7)  (the XOR swizzle).
    const int rowoff = (lane >> 3) * (D_DIM * 2) + (((lane & 7) ^ (lane >> 3)) << 4);
    const char* xh_w = (const char*)xh_g + (size_t)(pbase + wv * 32) * (D_DIM * 2) + rowoff;
    const char* xl_w = (const char*)xl_g + (size_t)(pbase + wv * 32) * (D_DIM * 2) + rowoff;
    char* ldsA_h = lds +         (wv * 32) * 128;   // wave-uniform DMA bases
    char* ldsA_l = lds + 16384 + (wv * 32) * 128;
    char* ldsB_h = lds + 32768 + (wv * 32) * 128;
    char* ldsB_l = lds + 49152 + (wv * 32) * 128;

    // fragment LDS byte offsets (constant across kt/dkc): row*128 + swizzled slot
    int aoff[4][2], boff[4][2];
#pragma unroll
    for (int i = 0; i < 4; ++i)
#pragma unroll
        for (int ks = 0; ks < 2; ++ks) {
            aoff[i][ks] = (wy * 64 + i * 16 + fr) * 128 + (((ks * 4 + g) ^ (fr & 7)) << 4);
            boff[i][ks] = 32768 + (wx * 64 + i * 16 + fr) * 128 + (((ks * 4 + g) ^ (fr & 7)) << 4);
        }

    float best[16];
    int   bidx[16];
#pragma unroll
    for (int i = 0; i < 16; ++i) { best[i] = 3.4e38f; bidx[i] = 0; }

    for (int kt = 0; kt < NTILES; ++kt) {
        const int ktbase = kbase + kt * TN;
        const char* ch_w = (const char*)ch_g + (size_t)(ktbase + wv * 32) * (D_DIM * 2) + rowoff;
        const char* cl_w = (const char*)cl_g + (size_t)(ktbase + wv * 32) * (D_DIM * 2) + rowoff;

        f32x4 acc[4][4];
#pragma unroll
        for (int i = 0; i < 4; ++i)
#pragma unroll
            for (int j = 0; j < 4; ++j) {
                f32x4 z = {0.f, 0.f, 0.f, 0.f};
                acc[i][j] = z;
            }

#pragma unroll 1
        for (int dkc = 0; dkc < 4; ++dkc) {      // 64-halves K chunks
            const int gofs = dkc * 128;          // byte offset into each row
            __syncthreads();                      // readers of prev chunk done
#pragma unroll
            for (int q = 0; q < 4; ++q) {        // 8 rows per inst, 32 rows/wave
                gld16(xh_w + q * 4096 + gofs, ldsA_h + q * 1024);
                gld16(xl_w + q * 4096 + gofs, ldsA_l + q * 1024);
                gld16(ch_w + q * 4096 + gofs, ldsB_h + q * 1024);
                gld16(cl_w + q * 4096 + gofs, ldsB_l + q * 1024);
            }
            __syncthreads();                      // barrier drains vmcnt (m97)
#pragma unroll
            for (int ks = 0; ks < 2; ++ks) {
                half8v a1[4], a2[4], a3[4];
#pragma unroll
                for (int i = 0; i < 4; ++i) {
                    const char* p = lds + aoff[i][ks];
                    a1[i] = *(const half8v*)p;              // xh
                    a3[i] = *(const half8v*)(p + 16384);    // xl*2^11
                    a2[i] = a1[i] * (_Float16)4.8828125e-4f; // xh*2^-11
                }
#pragma unroll
                for (int j = 0; j < 4; ++j) {
                    const char* p = lds + boff[j][ks];
                    half8v b1 = *(const half8v*)p;              // ch
                    half8v b2 = *(const half8v*)(p + 16384);    // cl*2^11
                    half8v b3 = b1 * (_Float16)4.8828125e-4f;   // ch*2^-11
#pragma unroll
                    for (int i = 0; i < 4; ++i) {
                        acc[i][j] = __builtin_amdgcn_mfma_f32_16x16x32_f16(a1[i], b1, acc[i][j], 0, 0, 0);
                        acc[i][j] = __builtin_amdgcn_mfma_f32_16x16x32_f16(a2[i], b2, acc[i][j], 0, 0, 0);
                        acc[i][j] = __builtin_amdgcn_mfma_f32_16x16x32_f16(a3[i], b3, acc[i][j], 0, 0, 0);
                    }
                }
            }
        }

        // merge tile into running argmin; ascending j + strict < == np first-min
#pragma unroll
        for (int j = 0; j < 4; ++j) {
            const int cg = ktbase + wx * 64 + j * 16 + fr;
            const float c2v = c2[cg];
#pragma unroll
            for (int i = 0; i < 4; ++i)
#pragma unroll
                for (int r = 0; r < 4; ++r) {
                    const float v = fmaf(-2.0f, acc[i][j][r], c2v);
                    const int s = i * 4 + r;
                    if (v < best[s]) { best[s] = v; bidx[s] = cg; }
                }
        }
    }

    // reduce across the 16 lanes holding each point row, then the 2 wave-cols
    __syncthreads();
    float* rd = (float*)lds;          // 128 x 2 floats
    int*   ri = (int*)lds + 256;      // 128 x 2 ints
#pragma unroll
    for (int i = 0; i < 4; ++i)
#pragma unroll
        for (int r = 0; r < 4; ++r) {
            float bv = best[i * 4 + r];
            int   bi = bidx[i * 4 + r];
#pragma unroll
            for (int off = 1; off < 16; off <<= 1) {
                const float ov = __shfl_xor(bv, off, 64);
                const int   oi = __shfl_xor(bi, off, 64);
                if (ov < bv || (ov == bv && oi < bi)) { bv = ov; bi = oi; }
            }
            if (fr == 0) {
                const int rowl = wy * 64 + i * 16 + g * 4 + r;
                rd[rowl * 2 + wx] = bv;
                ri[rowl * 2 + wx] = bi;
            }
        }
    __syncthreads();
    if (t < TM) {
        float b0 = rd[t * 2];
        int   i0 = ri[t * 2];
        const float b1 = rd[t * 2 + 1];
        const int   i1 = ri[t * 2 + 1];
        if (b1 < b0 || (b1 == b0 && i1 < i0)) { b0 = b1; i0 = i1; }
        pd[split * N_PTS + pbase + t] = b0;
        pi[split * N_PTS + pbase + t] = i0;
    }
}

// ---------------- fallback (round-3, passing) ----------------

#define BK 32
#define LS (BK + 4)

__device__ inline half8v load8(const _Float16* p) {
    half4v a = *(const half4v*)p;
    half4v b = *(const half4v*)(p + 4);
    return __builtin_shufflevector(a, b, 0, 1, 2, 3, 4, 5, 6, 7);
}

struct Trip { _Float16 h, s2, l2; };

__device__ inline Trip cvt3(float v) {
    Trip t;
    _Float16 hh = (_Float16)v;
    float hf = (float)hh;
    t.h  = hh;
    t.s2 = (_Float16)(hf * 4.8828125e-4f);
    t.l2 = (_Float16)((v - hf) * 2048.0f);
    return t;
}

__global__ void __launch_bounds__(256, 2)
vq_main_v3(const float* __restrict__ x, const float* __restrict__ vecs,
           const float* __restrict__ c2, float* __restrict__ pd, int* __restrict__ pi) {
    __shared__ _Float16 lds[6 * TM * LS];
    _Float16* xh  = lds;
    _Float16* xs2 = lds + 1 * TM * LS;
    _Float16* xl2 = lds + 2 * TM * LS;
    _Float16* ch  = lds + 3 * TM * LS;
    _Float16* cl2 = lds + 4 * TM * LS;
    _Float16* cs2 = lds + 5 * TM * LS;

    const int t     = threadIdx.x;
    const int split = blockIdx.x & (SPLITK - 1);
    const int pbase = (blockIdx.x >> 2) * TM;
    const int kbase = split * KCHUNK;

    const int lane = t & 63;
    const int wv   = t >> 6;
    const int wy   = wv >> 1, wx = wv & 1;
    const int fr   = lane & 15;
    const int g    = lane >> 4;
    const int kb   = g * 8;

    const int srow = t >> 3;
    const int sc4  = (t & 7) * 4;

    float best[16];
    int   bidx[16];
#pragma unroll
    for (int i = 0; i < 16; ++i) { best[i] = 3.4e38f; bidx[i] = 0; }

    for (int kt = 0; kt < NTILES; ++kt) {
        const int ktbase = kbase + kt * TN;
        f32x4 acc[4][4];
#pragma unroll
        for (int i = 0; i < 4; ++i)
#pragma unroll
            for (int j = 0; j < 4; ++j) {
                f32x4 z = {0.f, 0.f, 0.f, 0.f};
                acc[i][j] = z;
            }
        for (int dk = 0; dk < D_DIM; dk += BK) {
            __syncthreads();
#pragma unroll
            for (int p = 0; p < 4; ++p) {
                const int row = srow + p * 32;
                const float4 v = *(const float4*)&x[(size_t)(pbase + row) * D_DIM + dk + sc4];
                const Trip t0 = cvt3(v.x), t1 = cvt3(v.y), t2 = cvt3(v.z), t3 = cvt3(v.w);
                half4v h  = {t0.h,  t1.h,  t2.h,  t3.h};
                half4v s2 = {t0.s2, t1.s2, t2.s2, t3.s2};
                half4v l2 = {t0.l2, t1.l2, t2.l2, t3.l2};
                *(half4v*)&xh [row * LS + sc4] = h;
                *(half4v*)&xs2[row * LS + sc4] = s2;
                *(half4v*)&xl2[row * LS + sc4] = l2;
                const float4 w = *(const float4*)&vecs[(size_t)(ktbase + row) * D_DIM + dk + sc4];
                const Trip u0 = cvt3(w.x), u1 = cvt3(w.y), u2 = cvt3(w.z), u3 = cvt3(w.w);
                half4v hc = {u0.h,  u1.h,  u2.h,  u3.h};
                half4v sc = {u0.s2, u1.s2, u2.s2, u3.s2};
                half4v lc = {u0.l2, u1.l2, u2.l2, u3.l2};
                *(half4v*)&ch [row * LS + sc4] = hc;
                *(half4v*)&cs2[row * LS + sc4] = sc;
                *(half4v*)&cl2[row * LS + sc4] = lc;
            }
            __syncthreads();
            half8v a1[4], a2[4], a3[4], b1[4], b2[4], b3[4];
#pragma unroll
            for (int i = 0; i < 4; ++i) {
                const int aoff = (wy * 64 + i * 16 + fr) * LS + kb;
                a1[i] = load8(&xh [aoff]);
                a2[i] = load8(&xs2[aoff]);
                a3[i] = load8(&xl2[aoff]);
                const int boff2 = (wx * 64 + i * 16 + fr) * LS + kb;
                b1[i] = load8(&ch [boff2]);
                b2[i] = load8(&cl2[boff2]);
                b3[i] = load8(&cs2[boff2]);
            }
#pragma unroll
            for (int i = 0; i < 4; ++i)
#pragma unroll
                for (int j = 0; j < 4; ++j) {
                    acc[i][j] = __builtin_amdgcn_mfma_f32_16x16x32_f16(a1[i], b1[j], acc[i][j], 0, 0, 0);
                    acc[i][j] = __builtin_amdgcn_mfma_f32_16x16x32_f16(a2[i], b2[j], acc[i][j], 0, 0, 0);
                    acc[i][j] = __builtin_amdgcn_mfma_f32_16x16x32_f16(a3[i], b3[j], acc[i][j], 0, 0, 0);
                }
        }
#pragma unroll
        for (int j = 0; j < 4; ++j) {
            const int cg = ktbase + wx * 64 + j * 16 + fr;
            const float c2v = c2[cg];
#pragma unroll
            for (int i = 0; i < 4; ++i)
#pragma unroll
                for (int r = 0; r < 4; ++r) {
                    const float v = fmaf(-2.0f, acc[i][j][r], c2v);
                    const int s = i * 4 + r;
                    if (v < best[s]) { best[s] = v; bidx[s] = cg; }
                }
        }
    }
    __syncthreads();
    float* rd = (float*)lds;
    int*   ri = (int*)lds + 256;
#pragma unroll
    for (int i = 0; i < 4; ++i)
#pragma unroll
        for (int r = 0; r < 4; ++r) {
            float bv = best[i * 4 + r];
            int   bi = bidx[i * 4 + r];
#pragma unroll
            for (int off = 1; off < 16; off <<= 1) {
                const float ov = __shfl_xor(bv, off, 64);
                const int   oi = __shfl_xor(bi, off, 64);
                if (ov < bv || (ov == bv && oi < bi)) { bv = ov; bi = oi; }
            }
            if (fr == 0) {
                const int rowl = wy * 64 + i * 16 + g * 4 + r;
                rd[rowl * 2 + wx] = bv;
                ri[rowl * 2 + wx] = bi;
            }
        }
    __syncthreads();
    if (t < TM) {
        float b0 = rd[t * 2];
        int   i0 = ri[t * 2];
        const float b1 = rd[t * 2 + 1];
        const int   i1 = ri[t * 2 + 1];
        if (b1 < b0 || (b1 == b0 && i1 < i0)) { b0 = b1; i0 = i1; }
        pd[split * N_PTS + pbase + t] = b0;
        pi[split * N_PTS + pbase + t] = i0;
    }
}

// ---------------- combine ----------------

__global__ void __launch_bounds__(256)
vq_combine(const float* __restrict__ pd, const int* __restrict__ pi,
           int* __restrict__ out) {
    const int p = blockIdx.x * 256 + threadIdx.x;
    float bb = pd[p];
    int   bi = pi[p];
#pragma unroll
    for (int s = 1; s < SPLITK; ++s) {
        const float v  = pd[s * N_PTS + p];
        const int   vi = pi[s * N_PTS + p];
        if (v < bb || (v == bb && vi < bi)) { bb = v; bi = vi; }
    }
    out[p] = bi;
}

extern "C" void kernel_launch(void* const* d_in, const int* in_sizes, int n_in,
                              void* d_out, int out_size, void* d_ws, size_t ws_size,
                              hipStream_t stream) {
    const float* x    = (const float*)d_in[0];
    const float* vecs = (const float*)d_in[1];
    int* out = (int*)d_out;
    char* ws = (char*)d_ws;

    if (ws_size >= (size_t)WS_END) {
        _Float16* xh = (_Float16*)(ws + WS_XH);
        _Float16* xl = (_Float16*)(ws + WS_XL);
        _Float16* ch = (_Float16*)(ws + WS_CH);
        _Float16* cl = (_Float16*)(ws + WS_CL);
        float* c2 = (float*)(ws + WS_C2);
        float* pd = (float*)(ws + WS_PD);
        int*   pi = (int*)(ws + WS_PI);

        hipLaunchKernelGGL(prep_kernel, dim3(XBLOCKS + CBLOCKS), dim3(256), 0, stream,
                           x, vecs, xh, xl, ch, cl, c2);
        hipLaunchKernelGGL(vq_main_fast, dim3((N_PTS / TM) * SPLITK), dim3(256), 0, stream,
                           xh, xl, ch, cl, c2, pd, pi);
        hipLaunchKernelGGL(vq_combine, dim3(N_PTS / 256), dim3(256), 0, stream,
                           pd, pi, out);
    } else {
        float* c2 = (float*)ws;
        float* pd = (float*)ws + K_CB;
        int*   pi = (int*)((float*)ws + K_CB + SPLITK * N_PTS);
        hipLaunchKernelGGL(cnorms_kernel, dim3(K_CB / 4), dim3(256), 0, stream,
                           vecs, c2);
        hipLaunchKernelGGL(vq_main_v3, dim3((N_PTS / TM) * SPLITK), dim3(256), 0, stream,
                           x, vecs, c2, pd, pi);
        hipLaunchKernelGGL(vq_combine, dim3(N_PTS / 256), dim3(256), 0, stream,
                           pd, pi, out);
    }
}